// Round 10
// baseline (395.521 us; speedup 1.0000x reference)
//
#include <hip/hip_runtime.h>
#include <hip/hip_bf16.h>

using bf16 = __hip_bfloat16;

using frag_ab = __attribute__((ext_vector_type(8))) short;  // 8 bf16 = 4 VGPRs
using frag_cd = __attribute__((ext_vector_type(4))) float;  // 4 fp32 acc

__device__ __forceinline__ unsigned short f2bu(float f) {
    bf16 h = __float2bfloat16(f);
    return *(unsigned short*)&h;
}

__device__ __forceinline__ void st_c(float* p, float v) { *p = v; }
__device__ __forceinline__ void st_c(bf16* p, float v)  { *p = __float2bfloat16(v); }

// 16B-per-lane async global->LDS. Per-wave LDS dest = uniform base + lane*16.
__device__ __forceinline__ void load16(const bf16* g, bf16* l) {
    __builtin_amdgcn_global_load_lds(
        (const __attribute__((address_space(1))) unsigned int*)g,
        (__attribute__((address_space(3))) unsigned int*)l,
        16, 0, 0);
}

// ---------------------------------------------------------------------------
// Round 10 = session-best r3/r9 with ONE change: waitcnt inline asm has NO
// "memory" clobber (bare `asm volatile("s_waitcnt vmcnt(N)")`).
// Hypothesis (retrodicts r1/r2/r3 being identical regardless of vmcnt N):
// SIInsertWaitcnts treats memory-clobbered asm as an unknown memory access
// and inserts a full vmcnt(0)+lgkmcnt(0) drain before it -- so the counted
// vmcnt(6) never took effect and every even phase ate full HBM latency for
// all outstanding global_load_lds. m201's template writes these asm bare.
// Order safety without the clobber: each VMW is pinned by sched_barrier(0)
// above and s_barrier below (machine scheduler), and IR motion of LDS reads
// across phases is blocked by may-aliasing global_load_lds LDS writes.
// Everything else byte-identical to r9 (375.6/385.3us, absmax 0.0039).
// ---------------------------------------------------------------------------
template <typename TC, bool HAS_BIAS, bool MASK>
__global__ __launch_bounds__(512, 2)
void gemm8p(const bf16* __restrict__ A, const bf16* __restrict__ B,
            const float* __restrict__ bias, const int* __restrict__ mask,
            TC* __restrict__ C, int K, int lda, int ldb, int ldc,
            long sA, long sB, long sC, long sM, float scale)
{
    __shared__ short lds[65536];   // 4 slots x 16384 shorts = 128 KiB

    const int bz = blockIdx.z;
    const bf16* Ab = A + (long)bz * sA;
    const bf16* Bb = B + (long)bz * sB;
    TC* Cb = C + (long)bz * sC;
    const int* maskb = MASK ? (mask + (long)bz * sM) : nullptr;

    const int t    = threadIdx.x;
    const int wid  = t >> 6;
    const int lane = t & 63;
    const int m0 = blockIdx.x * 256;
    const int n0 = blockIdx.y * 256;
    const int wr = wid >> 2;       // 0..1  (M wave)
    const int wc = wid & 3;        // 0..3  (N wave)
    const int lrow = lane & 15;
    const int quad = lane >> 4;

    // reader-side swizzled 16B chunk: rotate by (row>>1)&3 (0 conflicts, r2-meas)
    const int rco   = ((quad + ((lrow >> 1) & 3)) & 3) * 8;   // shorts
    const int a_off = wr * 4096 + lrow * 32 + rco;   // + qm*2048 + i*512
    const int b_off = wc * 2048 + lrow * 32 + rco;   // + j*512 (B part +8192)

    // staging: each load16 covers 16 LDS rows (1024B linear); lane l -> row
    // l>>2, chunk l&3; global chunk pre-rotated: (c - (row>>1)) & 3.
    const int srow = wid * 32 + (lane >> 2);
    const int gk   = (((lane & 3) - (lane >> 3)) & 3) * 8;
    const bf16* srcA0 = Ab + (long)(m0 + srow) * lda + gk;
    const bf16* srcA1 = Ab + (long)(m0 + srow + 16) * lda + gk;
    const bf16* srcB0 = Bb + (long)(n0 + srow) * ldb + gk;
    const bf16* srcB1 = Bb + (long)(n0 + srow + 16) * ldb + gk;
    const int dst0 = wid * 1024 + lane * 8;          // shorts

    frag_cd acc[8][4] = {};
    frag_ab A0[4], A1[4], B0[4], B1[4];   // double-buffered fragments

#define STG(SLOT, PART, K0)                                                     \
    do {                                                                        \
        load16((PART ? srcB0 : srcA0) + (K0),                                   \
               (bf16*)&lds[(SLOT) * 16384 + (PART) * 8192 + dst0]);             \
        load16((PART ? srcB1 : srcA1) + (K0),                                   \
               (bf16*)&lds[(SLOT) * 16384 + (PART) * 8192 + dst0 + 512]);       \
    } while (0)

#define LOADA(DST, SLOT, QM)                                                    \
    do {                                                                        \
        _Pragma("unroll")                                                       \
        for (int i_ = 0; i_ < 4; ++i_)                                          \
            DST[i_] = *(const frag_ab*)&lds[(SLOT) * 16384 + a_off +            \
                                            (QM) * 2048 + i_ * 512];            \
    } while (0)

#define LOADB(DST, SLOT)                                                        \
    do {                                                                        \
        _Pragma("unroll")                                                       \
        for (int j_ = 0; j_ < 4; ++j_)                                          \
            DST[j_] = *(const frag_ab*)&lds[(SLOT) * 16384 + 8192 + b_off +     \
                                            j_ * 512];                          \
    } while (0)

#define MFMA16(AR, BR, QM)                                                      \
    do {                                                                        \
        _Pragma("unroll")                                                       \
        for (int i_ = 0; i_ < 4; ++i_)                                          \
            _Pragma("unroll")                                                   \
            for (int j_ = 0; j_ < 4; ++j_)                                      \
                acc[(QM) * 4 + i_][j_] = __builtin_amdgcn_mfma_f32_16x16x32_bf16( \
                    AR[i_], BR[j_], acc[(QM) * 4 + i_][j_], 0, 0, 0);           \
    } while (0)

// BARE waitcnt asm: no "memory" clobber (the round-10 single variable).
#define VMW(N)                                                                  \
    do {                                                                        \
        if ((N) == 6)      asm volatile("s_waitcnt vmcnt(6)");                  \
        else if ((N) == 4) asm volatile("s_waitcnt vmcnt(4)");                  \
        else if ((N) == 0) asm volatile("s_waitcnt vmcnt(0)");                  \
    } while (0)

// Phase: issue batch p+1 (ISSUE: 1=A only, 2=A+B) -> stage -> MFMA cluster p
// (compiler-counted lgkm on entry) -> optional vmcnt -> single end barrier.
#define PH(AR, BR, QM, ISSUE, NSLOT, NAR, NBR, NQM, DO_STG, SSLOT, SPART, SK0, VMN) \
    do {                                                                        \
        if ((ISSUE) >= 1) LOADA(NAR, NSLOT, NQM);                               \
        if ((ISSUE) == 2) LOADB(NBR, NSLOT);                                    \
        if (DO_STG) STG(SSLOT, SPART, SK0);                                     \
        __builtin_amdgcn_sched_barrier(0);                                      \
        __builtin_amdgcn_s_setprio(1);                                          \
        MFMA16(AR, BR, QM);                                                     \
        __builtin_amdgcn_s_setprio(0);                                          \
        __builtin_amdgcn_sched_barrier(0);                                      \
        VMW(VMN);                                                               \
        __builtin_amdgcn_s_barrier();                                           \
        __builtin_amdgcn_sched_barrier(0);                                      \
    } while (0)

    // prologue: slot0 = tile0 ks0, slot1 = tile0 ks1, slot2 = tile1 ks0
    STG(0, 0, 0);  STG(0, 1, 0);
    STG(1, 0, 32); STG(1, 1, 32);
    STG(2, 0, 64); STG(2, 1, 64);
    asm volatile("s_waitcnt vmcnt(8)");                // slot0 landed (bare)
    __builtin_amdgcn_sched_barrier(0);
    __builtin_amdgcn_s_barrier();
    __builtin_amdgcn_sched_barrier(0);
    LOADA(A0, 0, 0);      // batch 0 (cluster 0)
    LOADB(B0, 0);

    const int NI = K >> 7;   // 128 K per iteration (2 K-tiles); NI >= 2 here
    for (int it = 0; it < NI - 1; ++it) {
        const int kb = it << 7;
        //  cur    QM IS NS nxt      NQ STG SS SP SK0      VM
        PH(A0, B0, 0, 1, 0, A1, B1, 1, 1, 3, 0, kb + 96,   6);
        PH(A1, B0, 1, 2, 1, A0, B1, 0, 1, 3, 1, kb + 96,  -1);
        PH(A0, B1, 0, 1, 1, A1, B0, 1, 1, 0, 0, kb + 128,  6);
        PH(A1, B1, 1, 2, 2, A0, B0, 0, 1, 0, 1, kb + 128, -1);
        PH(A0, B0, 0, 1, 2, A1, B1, 1, 1, 1, 0, kb + 160,  6);
        PH(A1, B0, 1, 2, 3, A0, B1, 0, 1, 1, 1, kb + 160, -1);
        PH(A0, B1, 0, 1, 3, A1, B0, 1, 1, 2, 0, kb + 192,  6);
        PH(A1, B1, 1, 2, 0, A0, B0, 0, 1, 2, 1, kb + 192, -1);
    }
    {   // peeled last iteration: only slot3 (ks1 of last tile) still staged
        const int kb = (NI - 1) << 7;
        PH(A0, B0, 0, 1, 0, A1, B1, 1, 1, 3, 0, kb + 96,   6);
        PH(A1, B0, 1, 2, 1, A0, B1, 0, 1, 3, 1, kb + 96,  -1);
        PH(A0, B1, 0, 1, 1, A1, B0, 1, 0, 0, 0, 0,         4);
        PH(A1, B1, 1, 2, 2, A0, B0, 0, 0, 0, 0, 0,        -1);
        PH(A0, B0, 0, 1, 2, A1, B1, 1, 0, 0, 0, 0,         0);
        PH(A1, B0, 1, 2, 3, A0, B1, 0, 0, 0, 0, 0,        -1);
        PH(A0, B1, 0, 1, 3, A1, B0, 1, 0, 0, 0, 0,        -1);
        PH(A1, B1, 1, 0, 0, A0, B0, 0, 0, 0, 0, 0,        -1);
    }
#undef PH
#undef VMW
#undef MFMA16
#undef LOADB
#undef LOADA
#undef STG

    // epilogue: C/D layout col=lane&15, row=quad*4+reg  [m89-verified]
#pragma unroll
    for (int j = 0; j < 4; ++j) {
        const int col = n0 + wc * 64 + j * 16 + lrow;
        const float bv = HAS_BIAS ? bias[col] : 0.0f;
        const bool msk = MASK ? (maskb[col] != 0) : false;
#pragma unroll
        for (int ai = 0; ai < 8; ++ai) {
            const int rbase = m0 + wr * 128 + ai * 16 + quad * 4;
#pragma unroll
            for (int r = 0; r < 4; ++r) {
                float v = acc[ai][j][r] * scale + bv;
                if (MASK && msk) v = -INFINITY;
                st_c(&Cb[(long)(rbase + r) * ldc + col], v);
            }
        }
    }
}

// fp32 X[b][s][h] -> bf16 Xb[b][s][h] and bf16 XT[b][h][s], 64x64 tiles.
__global__ __launch_bounds__(256)
void convert_transpose(const float* __restrict__ X, bf16* __restrict__ Xb,
                       bf16* __restrict__ XT, int S, int H)
{
    __shared__ unsigned short tile[64][72];
    const int b = blockIdx.z;
    const float* Xp = X + (long)b * S * H;
    bf16* Xbp = Xb + (long)b * S * H;
    bf16* XTp = XT + (long)b * H * S;
    const int h0 = blockIdx.x * 64, s0 = blockIdx.y * 64;
    const int t = threadIdx.x;
    const int r  = t >> 4;
    const int c4 = (t & 15) * 4;

#pragma unroll
    for (int p = 0; p < 4; ++p) {
        const int row = r + p * 16;
        const float4 v = *(const float4*)&Xp[(long)(s0 + row) * H + h0 + c4];
        ushort4 u;
        u.x = f2bu(v.x); u.y = f2bu(v.y); u.z = f2bu(v.z); u.w = f2bu(v.w);
        *(ushort4*)&tile[row][c4] = u;
        *(ushort4*)&Xbp[(long)(s0 + row) * H + h0 + c4] = u;
    }
    __syncthreads();
#pragma unroll
    for (int p = 0; p < 4; ++p) {
        const int hrow = r + p * 16;
        ushort4 u;
        u.x = tile[c4 + 0][hrow];
        u.y = tile[c4 + 1][hrow];
        u.z = tile[c4 + 2][hrow];
        u.w = tile[c4 + 3][hrow];
        *(ushort4*)&XTp[(long)(h0 + hrow) * S + s0 + c4] = u;
    }
}

// both weight matrices -> bf16, contiguous out [2*H*H]
__global__ __launch_bounds__(256)
void convert_w2(const float* __restrict__ wa, const float* __restrict__ wb,
                bf16* __restrict__ out, int n4each)
{
    const int i = blockIdx.x * 256 + threadIdx.x;
    const bool second = i >= n4each;
    const float* src = second ? wb : wa;
    const int j = second ? i - n4each : i;
    const float4 v = ((const float4*)src)[j];
    ushort4 u;
    u.x = f2bu(v.x); u.y = f2bu(v.y); u.z = f2bu(v.z); u.w = f2bu(v.w);
    ((ushort4*)out)[i] = u;
}

__global__ __launch_bounds__(256)
void pack_bias(const float* __restrict__ qb, const float* __restrict__ kb,
               float* __restrict__ out, int H)
{
    const int i = blockIdx.x * 256 + threadIdx.x;
    out[i] = (i < H) ? qb[i] : kb[i - H];
}

// In-place masked softmax over rows (Slen=2048 bf16). Mask pre-applied as -inf.
__global__ __launch_bounds__(256)
void softmax_kernel(bf16* __restrict__ Smat, int Slen)
{
    const int row = blockIdx.x;
    bf16* srow = Smat + (long)row * Slen;

    const int t    = threadIdx.x;
    const int lane = t & 63;
    const int wid  = t >> 6;

    ushort4 u0 = ((const ushort4*)srow)[t * 2];
    ushort4 u1 = ((const ushort4*)srow)[t * 2 + 1];

    float vals[8];
    {
        const unsigned short us[8] = {u0.x, u0.y, u0.z, u0.w, u1.x, u1.y, u1.z, u1.w};
#pragma unroll
        for (int i = 0; i < 8; ++i) {
            unsigned int w = (unsigned int)us[i] << 16;
            vals[i] = *(float*)&w;
        }
    }

    float mx = vals[0];
#pragma unroll
    for (int i = 1; i < 8; ++i) mx = fmaxf(mx, vals[i]);

    __shared__ float red[4];
#pragma unroll
    for (int o = 32; o > 0; o >>= 1) mx = fmaxf(mx, __shfl_xor(mx, o, 64));
    if (lane == 0) red[wid] = mx;
    __syncthreads();
    mx = fmaxf(fmaxf(red[0], red[1]), fmaxf(red[2], red[3]));
    __syncthreads();

    float sum = 0.0f;
#pragma unroll
    for (int i = 0; i < 8; ++i) {
        const float e = __expf(vals[i] - mx);   // exp(-inf - mx) = 0
        vals[i] = e;
        sum += e;
    }
#pragma unroll
    for (int o = 32; o > 0; o >>= 1) sum += __shfl_xor(sum, o, 64);
    if (lane == 0) red[wid] = sum;
    __syncthreads();
    sum = red[0] + red[1] + red[2] + red[3];

    const float inv = 1.0f / sum;
    ushort4 o0, o1;
    o0.x = f2bu(vals[0] * inv); o0.y = f2bu(vals[1] * inv);
    o0.z = f2bu(vals[2] * inv); o0.w = f2bu(vals[3] * inv);
    o1.x = f2bu(vals[4] * inv); o1.y = f2bu(vals[5] * inv);
    o1.z = f2bu(vals[6] * inv); o1.w = f2bu(vals[7] * inv);
    ((ushort4*)srow)[t * 2]     = o0;
    ((ushort4*)srow)[t * 2 + 1] = o1;
}

extern "C" void kernel_launch(void* const* d_in, const int* in_sizes, int n_in,
                              void* d_out, int out_size, void* d_ws, size_t ws_size,
                              hipStream_t stream)
{
    const float* hidden = (const float*)d_in[0];
    const int*   mask   = (const int*)d_in[1];
    const float* Wq_w   = (const float*)d_in[2];
    const float* Wq_b   = (const float*)d_in[3];
    const float* Wk_w   = (const float*)d_in[4];
    const float* Wk_b   = (const float*)d_in[5];
    float* out = (float*)d_out;

    const int B = 8, S = 2048, H = 1024;
    const int M = B * S;               // 16384
    const long MH = (long)M * H;       // 16.7M elems

    // ws (bf16 elems): QK[M][2H] (67MB) | XbT (33.5MB) | Sb (67MB)
    // Xb + Wb (stacked weights) + packed bias aliased inside Sb (dead before scores).
    bf16* QK  = (bf16*)d_ws;
    bf16* XbT = QK + MH * 2;
    bf16* Sb  = XbT + MH;
    bf16* Xb  = Sb;                    // aliased
    bf16* Wb  = Xb + MH;               // [2H][H] = Wq stacked on Wk
    float* biasP = (float*)(Wb + 2L * H * H);  // 2048 floats

    const dim3 blk(256);
    const dim3 blk512(512);

    convert_transpose<<<dim3(H / 64, S / 64, B), blk, 0, stream>>>(hidden, Xb, XbT, S, H);
    convert_w2<<<dim3(2 * H * H / 1024), blk, 0, stream>>>(Wq_w, Wk_w, Wb, H * H / 4);
    pack_bias<<<dim3(2 * H / 256), blk, 0, stream>>>(Wq_b, Wk_b, biasP, H);

    // QK = Xb @ [Wq;Wk]^T + [bq;bk]   (merged, N = 2H) : 16384 x 2048, K=1024
    gemm8p<bf16, true, false><<<dim3(M / 256, 2 * H / 256, 1), blk512, 0, stream>>>(
        Xb, Wb, biasP, nullptr, QK, H, H, H, 2 * H, 0, 0, 0, 0, 1.0f);

    // Scores_b = (Q_b @ K_b^T)/32, mask applied as -inf in epilogue : 2048x2048, K=1024
    gemm8p<bf16, false, true><<<dim3(S / 256, S / 256, B), blk512, 0, stream>>>(
        QK, QK + H, nullptr, mask, Sb, H, 2 * H, 2 * H, S,
        (long)S * 2 * H, (long)S * 2 * H, (long)S * S, S, 1.0f / 32.0f);

    // softmax in place (mask already -inf)
    softmax_kernel<<<dim3(B * S), blk, 0, stream>>>(Sb, S);

    // Out_b = P_b @ X_b  (B operand = XbT, k-contig) : 2048x1024, K=2048
    gemm8p<float, false, false><<<dim3(S / 256, H / 256, B), blk512, 0, stream>>>(
        Sb, XbT, nullptr, nullptr, out, S, S, S, H,
        (long)S * S, (long)H * S, (long)S * H, 0, 1.0f);
}

// Round 11
// 377.278 us; speedup vs baseline: 1.0484x; 1.0484x over previous
//
#include <hip/hip_runtime.h>
#include <hip/hip_bf16.h>

using bf16 = __hip_bfloat16;

using frag_ab = __attribute__((ext_vector_type(8))) short;  // 8 bf16 = 4 VGPRs
using frag_cd = __attribute__((ext_vector_type(4))) float;  // 4 fp32 acc

__device__ __forceinline__ unsigned short f2bu(float f) {
    bf16 h = __float2bfloat16(f);
    return *(unsigned short*)&h;
}
__device__ __forceinline__ float bu2f(unsigned short u) {
    unsigned int w = (unsigned int)u << 16;
    return *(float*)&w;
}

__device__ __forceinline__ void st_c(float* p, float v) { *p = v; }
__device__ __forceinline__ void st_c(bf16* p, float v)  { *p = __float2bfloat16(v); }

// 16B-per-lane async global->LDS. Per-wave LDS dest = uniform base + lane*16.
__device__ __forceinline__ void load16(const bf16* g, bf16* l) {
    __builtin_amdgcn_global_load_lds(
        (const __attribute__((address_space(1))) unsigned int*)g,
        (__attribute__((address_space(3))) unsigned int*)l,
        16, 0, 0);
}

// ---------------------------------------------------------------------------
// Round 11 = r9 GEMM main loop BYTE-IDENTICAL + softmax deleted via the
// evidence-vetted combination:
//  * EXPOUT+XCDZ on scores: epilogue e=exp(s/32), mask->0. PROVEN 88us in r7
//    (r7's 192us outlier was a warmup artifact: MfmaUtil 0.7, Occ 1.1).
//  * rowinv kernel: 1/rowsum(E) -> f32[M] in the dead QK buffer (~12us read
//    pass) -- replaces the 134MB softmax RMW (~25-30us).
//  * ROWSCALE on PV: EPILOGUE-ONLY multiply by rinv[row] (L1-hot loads).
//    The toxic r7/r8 element was the IN-LOOP RSUM (189/224us both rounds);
//    this variant adds zero instructions to the K-loop.
//  * XCDZ (bijective, gridDim.z==8) on scores+PV: proven safe/better in r6.
// ROWSCALE reuses the bias param as the per-batch row-inv base (stride sM).
// ---------------------------------------------------------------------------
template <typename TC, bool HAS_BIAS, bool MASK, bool EXPOUT, bool ROWSCALE, bool XCDZ>
__global__ __launch_bounds__(512, 2)
void gemm8p(const bf16* __restrict__ A, const bf16* __restrict__ B,
            const float* __restrict__ bias, const int* __restrict__ mask,
            TC* __restrict__ C, int K, int lda, int ldb, int ldc,
            long sA, long sB, long sC, long sM, float scale)
{
    __shared__ short lds[65536];   // 4 slots x 16384 shorts = 128 KiB

    int bx = blockIdx.x, by = blockIdx.y, bz = blockIdx.z;
    if constexpr (XCDZ) {           // requires gridDim.z == 8; bijective
        const int L = bx + gridDim.x * (by + gridDim.y * bz);
        bz = L & 7;
        const int idx = L >> 3;
        bx = idx % gridDim.x;
        by = idx / gridDim.x;
    }

    const bf16* Ab = A + (long)bz * sA;
    const bf16* Bb = B + (long)bz * sB;
    TC* Cb = C + (long)bz * sC;
    const int* maskb = MASK ? (mask + (long)bz * sM) : nullptr;
    const float* rscb = ROWSCALE ? (bias + (long)bz * sM) : nullptr;

    const int t    = threadIdx.x;
    const int wid  = t >> 6;
    const int lane = t & 63;
    const int m0 = bx * 256;
    const int n0 = by * 256;
    const int wr = wid >> 2;       // 0..1  (M wave)
    const int wc = wid & 3;        // 0..3  (N wave)
    const int lrow = lane & 15;
    const int quad = lane >> 4;

    // reader-side swizzled 16B chunk: rotate by (row>>1)&3 (0 conflicts, r2-meas)
    const int rco   = ((quad + ((lrow >> 1) & 3)) & 3) * 8;   // shorts
    const int a_off = wr * 4096 + lrow * 32 + rco;   // + qm*2048 + i*512
    const int b_off = wc * 2048 + lrow * 32 + rco;   // + j*512 (B part +8192)

    // staging: each load16 covers 16 LDS rows (1024B linear); lane l -> row
    // l>>2, chunk l&3; global chunk pre-rotated: (c - (row>>1)) & 3.
    const int srow = wid * 32 + (lane >> 2);
    const int gk   = (((lane & 3) - (lane >> 3)) & 3) * 8;
    const bf16* srcA0 = Ab + (long)(m0 + srow) * lda + gk;
    const bf16* srcA1 = Ab + (long)(m0 + srow + 16) * lda + gk;
    const bf16* srcB0 = Bb + (long)(n0 + srow) * ldb + gk;
    const bf16* srcB1 = Bb + (long)(n0 + srow + 16) * ldb + gk;
    const int dst0 = wid * 1024 + lane * 8;          // shorts

    frag_cd acc[8][4] = {};
    frag_ab A0[4], A1[4], B0[4], B1[4];   // double-buffered fragments

#define STG(SLOT, PART, K0)                                                     \
    do {                                                                        \
        load16((PART ? srcB0 : srcA0) + (K0),                                   \
               (bf16*)&lds[(SLOT) * 16384 + (PART) * 8192 + dst0]);             \
        load16((PART ? srcB1 : srcA1) + (K0),                                   \
               (bf16*)&lds[(SLOT) * 16384 + (PART) * 8192 + dst0 + 512]);       \
    } while (0)

#define LOADA(DST, SLOT, QM)                                                    \
    do {                                                                        \
        _Pragma("unroll")                                                       \
        for (int i_ = 0; i_ < 4; ++i_)                                          \
            DST[i_] = *(const frag_ab*)&lds[(SLOT) * 16384 + a_off +            \
                                            (QM) * 2048 + i_ * 512];            \
    } while (0)

#define LOADB(DST, SLOT)                                                        \
    do {                                                                        \
        _Pragma("unroll")                                                       \
        for (int j_ = 0; j_ < 4; ++j_)                                          \
            DST[j_] = *(const frag_ab*)&lds[(SLOT) * 16384 + 8192 + b_off +     \
                                            j_ * 512];                          \
    } while (0)

#define MFMA16(AR, BR, QM)                                                      \
    do {                                                                        \
        _Pragma("unroll")                                                       \
        for (int i_ = 0; i_ < 4; ++i_)                                          \
            _Pragma("unroll")                                                   \
            for (int j_ = 0; j_ < 4; ++j_)                                      \
                acc[(QM) * 4 + i_][j_] = __builtin_amdgcn_mfma_f32_16x16x32_bf16( \
                    AR[i_], BR[j_], acc[(QM) * 4 + i_][j_], 0, 0, 0);           \
    } while (0)

#define VMW(N)                                                                  \
    do {                                                                        \
        if ((N) == 6)      asm volatile("s_waitcnt vmcnt(6)" ::: "memory");     \
        else if ((N) == 4) asm volatile("s_waitcnt vmcnt(4)" ::: "memory");     \
        else if ((N) == 0) asm volatile("s_waitcnt vmcnt(0)" ::: "memory");     \
    } while (0)

// Phase: issue batch p+1 (ISSUE: 1=A only, 2=A+B) -> stage -> MFMA cluster p
// (compiler-counted lgkm on entry) -> optional vmcnt -> single end barrier.
#define PH(AR, BR, QM, ISSUE, NSLOT, NAR, NBR, NQM, DO_STG, SSLOT, SPART, SK0, VMN) \
    do {                                                                        \
        if ((ISSUE) >= 1) LOADA(NAR, NSLOT, NQM);                               \
        if ((ISSUE) == 2) LOADB(NBR, NSLOT);                                    \
        if (DO_STG) STG(SSLOT, SPART, SK0);                                     \
        __builtin_amdgcn_sched_barrier(0);                                      \
        __builtin_amdgcn_s_setprio(1);                                          \
        MFMA16(AR, BR, QM);                                                     \
        __builtin_amdgcn_s_setprio(0);                                          \
        __builtin_amdgcn_sched_barrier(0);                                      \
        VMW(VMN);                                                               \
        __builtin_amdgcn_s_barrier();                                           \
        __builtin_amdgcn_sched_barrier(0);                                      \
    } while (0)

    // prologue: slot0 = tile0 ks0, slot1 = tile0 ks1, slot2 = tile1 ks0
    STG(0, 0, 0);  STG(0, 1, 0);
    STG(1, 0, 32); STG(1, 1, 32);
    STG(2, 0, 64); STG(2, 1, 64);
    asm volatile("s_waitcnt vmcnt(8)" ::: "memory");   // slot0 landed
    __builtin_amdgcn_sched_barrier(0);
    __builtin_amdgcn_s_barrier();
    __builtin_amdgcn_sched_barrier(0);
    LOADA(A0, 0, 0);      // batch 0 (cluster 0)
    LOADB(B0, 0);

    const int NI = K >> 7;   // 128 K per iteration (2 K-tiles); NI >= 2 here
    for (int it = 0; it < NI - 1; ++it) {
        const int kb = it << 7;
        //  cur    QM IS NS nxt      NQ STG SS SP SK0      VM
        PH(A0, B0, 0, 1, 0, A1, B1, 1, 1, 3, 0, kb + 96,   6);
        PH(A1, B0, 1, 2, 1, A0, B1, 0, 1, 3, 1, kb + 96,  -1);
        PH(A0, B1, 0, 1, 1, A1, B0, 1, 1, 0, 0, kb + 128,  6);
        PH(A1, B1, 1, 2, 2, A0, B0, 0, 1, 0, 1, kb + 128, -1);
        PH(A0, B0, 0, 1, 2, A1, B1, 1, 1, 1, 0, kb + 160,  6);
        PH(A1, B0, 1, 2, 3, A0, B1, 0, 1, 1, 1, kb + 160, -1);
        PH(A0, B1, 0, 1, 3, A1, B0, 1, 1, 2, 0, kb + 192,  6);
        PH(A1, B1, 1, 2, 0, A0, B0, 0, 1, 2, 1, kb + 192, -1);
    }
    {   // peeled last iteration: only slot3 (ks1 of last tile) still staged
        const int kb = (NI - 1) << 7;
        PH(A0, B0, 0, 1, 0, A1, B1, 1, 1, 3, 0, kb + 96,   6);
        PH(A1, B0, 1, 2, 1, A0, B1, 0, 1, 3, 1, kb + 96,  -1);
        PH(A0, B1, 0, 1, 1, A1, B0, 1, 0, 0, 0, 0,         4);
        PH(A1, B1, 1, 2, 2, A0, B0, 0, 0, 0, 0, 0,        -1);
        PH(A0, B0, 0, 1, 2, A1, B1, 1, 0, 0, 0, 0,         0);
        PH(A1, B0, 1, 2, 3, A0, B1, 0, 0, 0, 0, 0,        -1);
        PH(A0, B1, 0, 1, 3, A1, B0, 1, 0, 0, 0, 0,        -1);
        PH(A1, B1, 1, 0, 0, A0, B0, 0, 0, 0, 0, 0,        -1);
    }
#undef PH
#undef VMW
#undef MFMA16
#undef LOADB
#undef LOADA
#undef STG

    // ROWSCALE: fetch this thread's 32 row inverses (L1/L2-hot: 256 floats
    // shared by the whole block). Epilogue-only; K-loop untouched.
    float inv_l[8][4];
    if constexpr (ROWSCALE) {
#pragma unroll
        for (int ai = 0; ai < 8; ++ai)
#pragma unroll
            for (int r = 0; r < 4; ++r)
                inv_l[ai][r] = rscb[m0 + wr * 128 + ai * 16 + quad * 4 + r];
    }

    // epilogue: C/D layout col=lane&15, row=quad*4+reg  [m89-verified]
#pragma unroll
    for (int j = 0; j < 4; ++j) {
        const int col = n0 + wc * 64 + j * 16 + lrow;
        const float bv = HAS_BIAS ? bias[col] : 0.0f;
        const bool msk = MASK ? (maskb[col] != 0) : false;
#pragma unroll
        for (int ai = 0; ai < 8; ++ai) {
            const int rbase = m0 + wr * 128 + ai * 16 + quad * 4;
#pragma unroll
            for (int r = 0; r < 4; ++r) {
                float v = acc[ai][j][r] * scale + bv;
                if constexpr (EXPOUT) {
                    v = (MASK && msk) ? 0.0f : __expf(v);
                } else {
                    if (MASK && msk) v = -INFINITY;
                    if constexpr (ROWSCALE) v *= inv_l[ai][r];
                }
                st_c(&Cb[(long)(rbase + r) * ldc + col], v);
            }
        }
    }
}

// fp32 X[b][s][h] -> bf16 Xb[b][s][h] and bf16 XT[b][h][s], 64x64 tiles.
__global__ __launch_bounds__(256)
void convert_transpose(const float* __restrict__ X, bf16* __restrict__ Xb,
                       bf16* __restrict__ XT, int S, int H)
{
    __shared__ unsigned short tile[64][72];
    const int b = blockIdx.z;
    const float* Xp = X + (long)b * S * H;
    bf16* Xbp = Xb + (long)b * S * H;
    bf16* XTp = XT + (long)b * H * S;
    const int h0 = blockIdx.x * 64, s0 = blockIdx.y * 64;
    const int t = threadIdx.x;
    const int r  = t >> 4;
    const int c4 = (t & 15) * 4;

#pragma unroll
    for (int p = 0; p < 4; ++p) {
        const int row = r + p * 16;
        const float4 v = *(const float4*)&Xp[(long)(s0 + row) * H + h0 + c4];
        ushort4 u;
        u.x = f2bu(v.x); u.y = f2bu(v.y); u.z = f2bu(v.z); u.w = f2bu(v.w);
        *(ushort4*)&tile[row][c4] = u;
        *(ushort4*)&Xbp[(long)(s0 + row) * H + h0 + c4] = u;
    }
    __syncthreads();
#pragma unroll
    for (int p = 0; p < 4; ++p) {
        const int hrow = r + p * 16;
        ushort4 u;
        u.x = tile[c4 + 0][hrow];
        u.y = tile[c4 + 1][hrow];
        u.z = tile[c4 + 2][hrow];
        u.w = tile[c4 + 3][hrow];
        *(ushort4*)&XTp[(long)(h0 + hrow) * S + s0 + c4] = u;
    }
}

// both weight matrices -> bf16, contiguous out [2*H*H]
__global__ __launch_bounds__(256)
void convert_w2(const float* __restrict__ wa, const float* __restrict__ wb,
                bf16* __restrict__ out, int n4each)
{
    const int i = blockIdx.x * 256 + threadIdx.x;
    const bool second = i >= n4each;
    const float* src = second ? wb : wa;
    const int j = second ? i - n4each : i;
    const float4 v = ((const float4*)src)[j];
    ushort4 u;
    u.x = f2bu(v.x); u.y = f2bu(v.y); u.z = f2bu(v.z); u.w = f2bu(v.w);
    ((ushort4*)out)[i] = u;
}

__global__ __launch_bounds__(256)
void pack_bias(const float* __restrict__ qb, const float* __restrict__ kb,
               float* __restrict__ out, int H)
{
    const int i = blockIdx.x * 256 + threadIdx.x;
    out[i] = (i < H) ? qb[i] : kb[i - H];
}

// rinv[row] = 1 / sum_k E[row][k], one wave per row (Slen = 2048).
__global__ __launch_bounds__(256)
void rowinv(const bf16* __restrict__ E, float* __restrict__ rinv, int Slen)
{
    const int wid  = threadIdx.x >> 6;
    const int lane = threadIdx.x & 63;
    const long row = (long)blockIdx.x * 4 + wid;
    const bf16* e = E + row * Slen + lane * 32;   // 64 lanes x 32 elems

    float s = 0.0f;
#pragma unroll
    for (int c = 0; c < 4; ++c) {
        frag_ab u = *(const frag_ab*)(e + c * 8);
#pragma unroll
        for (int i = 0; i < 8; ++i) s += bu2f((unsigned short)u[i]);
    }
#pragma unroll
    for (int o = 32; o > 0; o >>= 1) s += __shfl_xor(s, o, 64);
    if (lane == 0) rinv[row] = 1.0f / s;
}

extern "C" void kernel_launch(void* const* d_in, const int* in_sizes, int n_in,
                              void* d_out, int out_size, void* d_ws, size_t ws_size,
                              hipStream_t stream)
{
    const float* hidden = (const float*)d_in[0];
    const int*   mask   = (const int*)d_in[1];
    const float* Wq_w   = (const float*)d_in[2];
    const float* Wq_b   = (const float*)d_in[3];
    const float* Wk_w   = (const float*)d_in[4];
    const float* Wk_b   = (const float*)d_in[5];
    float* out = (float*)d_out;

    const int B = 8, S = 2048, H = 1024;
    const int M = B * S;               // 16384
    const long MH = (long)M * H;       // 16.7M elems

    // ws (bf16 elems): QK[M][2H] (67MB) | XbT (33.5MB) | Sb (67MB)
    // Xb + Wb (stacked weights) + packed bias aliased inside Sb (dead before
    // scores writes Sb). rsums (f32[M], 64KB) aliases the QK buffer head --
    // QK is dead after the scores GEMM reads it; rowinv runs after scores.
    bf16* QK  = (bf16*)d_ws;
    bf16* XbT = QK + MH * 2;
    bf16* Sb  = XbT + MH;
    bf16* Xb  = Sb;                    // aliased
    bf16* Wb  = Xb + MH;               // [2H][H] = Wq stacked on Wk
    float* biasP = (float*)(Wb + 2L * H * H);  // 2048 floats
    float* rsums = (float*)QK;                 // f32[M], aliases dead QK

    const dim3 blk(256);
    const dim3 blk512(512);

    convert_transpose<<<dim3(H / 64, S / 64, B), blk, 0, stream>>>(hidden, Xb, XbT, S, H);
    convert_w2<<<dim3(2 * H * H / 1024), blk, 0, stream>>>(Wq_w, Wk_w, Wb, H * H / 4);
    pack_bias<<<dim3(2 * H / 256), blk, 0, stream>>>(Wq_b, Wk_b, biasP, H);

    // QK = Xb @ [Wq;Wk]^T + [bq;bk]   (merged, N = 2H) : 16384 x 2048, K=1024
    gemm8p<bf16, true, false, false, false, false>
        <<<dim3(M / 256, 2 * H / 256, 1), blk512, 0, stream>>>(
        Xb, Wb, biasP, nullptr, QK, H, H, H, 2 * H, 0, 0, 0, 0, 1.0f);

    // E_b = exp((Q_b @ K_b^T)/32), mask -> 0 : 2048x2048 x8, K=1024
    gemm8p<bf16, false, true, true, false, true>
        <<<dim3(S / 256, S / 256, B), blk512, 0, stream>>>(
        QK, QK + H, nullptr, mask, Sb, H, 2 * H, 2 * H, S,
        (long)S * 2 * H, (long)S * 2 * H, (long)S * S, S, 1.0f / 32.0f);

    // rinv[m] = 1 / rowsum(E)   (reads 67MB; QK buffer now dead -> reuse)
    rowinv<<<dim3(M / 4), blk, 0, stream>>>(Sb, rsums, S);

    // Out_b = (E_b @ X_b) * rinv : 2048x1024 x8, K=2048
    gemm8p<float, false, false, false, true, true>
        <<<dim3(S / 256, H / 256, B), blk512, 0, stream>>>(
        Sb, XbT, rsums, nullptr, out, S, S, S, H,
        (long)S * S, (long)H * S, (long)S * H, S, 1.0f);
}